// Round 1
// baseline (2252.703 us; speedup 1.0000x reference)
//
#include <hip/hip_runtime.h>

namespace {
constexpr int Bn  = 4;
constexpr int Tn  = 2048;
constexpr int Dn  = 1024;
constexpr int Hn  = 16;
constexpr int HSn = 64;
}

// ---------------------------------------------------------------------------
// QKV projection: per (proj, b, h): X[b] (T x D) @ W[h] (D x HS) -> [T x HS]
// grid: (T/64, 3*B*H), block 256. 64x64 tile, K-chunks of 32.
// ---------------------------------------------------------------------------
__global__ __launch_bounds__(256) void qkv_kernel(
    const float* __restrict__ x, const float* __restrict__ Wq,
    const float* __restrict__ Wk, const float* __restrict__ Wv,
    float* __restrict__ qo, float* __restrict__ ko, float* __restrict__ vo)
{
    const int proj = blockIdx.y >> 6;      // 0,1,2 = q,k,v
    const int bh   = blockIdx.y & 63;      // b*H + h
    const float* W   = (proj == 0) ? Wq : (proj == 1) ? Wk : Wv;
    float*       out = (proj == 0) ? qo : (proj == 1) ? ko : vo;
    const int h = bh & 15;
    const float* Wh = W + (size_t)h * Dn * HSn;
    const float* xb = x + ((size_t)(bh >> 4) * Tn + blockIdx.x * 64) * Dn;
    float*       ob = out + ((size_t)bh * Tn + blockIdx.x * 64) * HSn;

    __shared__ float Xs[64][33];   // +1 pad: reads stride the row dim
    __shared__ float Ws[32][64];   // row-broadcast reads, keep aligned

    const int tid = threadIdx.x;
    const int ty = tid >> 4, tx = tid & 15;

    float acc[4][4] = {};
    for (int k0 = 0; k0 < Dn; k0 += 32) {
        {
            const int r  = tid >> 3;            // 0..31
            const int c4 = (tid & 7) << 2;      // 0..28
            #pragma unroll
            for (int p = 0; p < 2; ++p) {
                const float4 t = *(const float4*)(xb + (size_t)(r + p * 32) * Dn + k0 + c4);
                Xs[r + p * 32][c4 + 0] = t.x; Xs[r + p * 32][c4 + 1] = t.y;
                Xs[r + p * 32][c4 + 2] = t.z; Xs[r + p * 32][c4 + 3] = t.w;
            }
            const int rw = tid >> 4;            // 0..15
            const int cw = (tid & 15) << 2;     // 0..60
            #pragma unroll
            for (int p = 0; p < 2; ++p)
                *(float4*)&Ws[rw + p * 16][cw] =
                    *(const float4*)(Wh + (size_t)(k0 + rw + p * 16) * HSn + cw);
        }
        __syncthreads();
        #pragma unroll
        for (int kk = 0; kk < 32; ++kk) {
            float a[4];
            #pragma unroll
            for (int i = 0; i < 4; ++i) a[i] = Xs[ty * 4 + i][kk];
            const float4 bv = *(const float4*)&Ws[kk][tx * 4];
            #pragma unroll
            for (int i = 0; i < 4; ++i) {
                acc[i][0] = fmaf(a[i], bv.x, acc[i][0]);
                acc[i][1] = fmaf(a[i], bv.y, acc[i][1]);
                acc[i][2] = fmaf(a[i], bv.z, acc[i][2]);
                acc[i][3] = fmaf(a[i], bv.w, acc[i][3]);
            }
        }
        __syncthreads();
    }
    #pragma unroll
    for (int i = 0; i < 4; ++i) {
        float4 t;
        t.x = acc[i][0]; t.y = acc[i][1]; t.z = acc[i][2]; t.w = acc[i][3];
        *(float4*)(ob + (size_t)(ty * 4 + i) * HSn + tx * 4) = t;
    }
}

// ---------------------------------------------------------------------------
// Causal flash attention. grid: (T/64 q-tiles, B*H), block 256.
// Q-tile 64x64 resident; stream K/V tiles of 64 with online softmax.
// ---------------------------------------------------------------------------
__global__ __launch_bounds__(256) void attn_kernel(
    const float* __restrict__ q, const float* __restrict__ k,
    const float* __restrict__ v, float* __restrict__ o)
{
    const int qt = blockIdx.x;
    const int bh = blockIdx.y;
    const float* qb = q + ((size_t)bh * Tn + qt * 64) * HSn;
    const float* kb = k + (size_t)bh * Tn * HSn;
    const float* vb = v + (size_t)bh * Tn * HSn;

    __shared__ float Qs[64][65];   // padded: S-compute reads stride row dim
    __shared__ float Ks[64][65];   // padded: same
    __shared__ float Vs[64][64];   // row-broadcast reads, aligned float4
    __shared__ float Ps[64][65];   // padded: PV reads stride row dim

    const int tid = threadIdx.x;
    const int ty = tid >> 4, tx = tid & 15;

    float o_acc[4][4] = {};
    float m_i[4], l_i[4];
    #pragma unroll
    for (int i = 0; i < 4; ++i) { m_i[i] = -1e30f; l_i[i] = 0.f; }

    for (int li = tid; li < 64 * 16; li += 256) {
        const int r = li >> 4;
        const int c4 = (li & 15) << 2;
        const float4 t = *(const float4*)(qb + (size_t)r * HSn + c4);
        Qs[r][c4 + 0] = t.x; Qs[r][c4 + 1] = t.y;
        Qs[r][c4 + 2] = t.z; Qs[r][c4 + 3] = t.w;
    }

    const float scale = 0.125f;  // HS^-0.5 = 1/8

    for (int kt = 0; kt <= qt; ++kt) {
        __syncthreads();   // prev PV done (and first-iter Q load visible)
        for (int li = tid; li < 64 * 16; li += 256) {
            const int r = li >> 4;
            const int c4 = (li & 15) << 2;
            const float4 t = *(const float4*)(kb + (size_t)(kt * 64 + r) * HSn + c4);
            Ks[r][c4 + 0] = t.x; Ks[r][c4 + 1] = t.y;
            Ks[r][c4 + 2] = t.z; Ks[r][c4 + 3] = t.w;
            *(float4*)&Vs[r][c4] = *(const float4*)(vb + (size_t)(kt * 64 + r) * HSn + c4);
        }
        __syncthreads();   // K/V ready

        // S = Q K^T (thread owns rows ty*4+i, cols tx*4+j)
        float s[4][4] = {};
        #pragma unroll 16
        for (int e = 0; e < 64; ++e) {
            float a[4], bb[4];
            #pragma unroll
            for (int i = 0; i < 4; ++i) a[i] = Qs[ty * 4 + i][e];
            #pragma unroll
            for (int j = 0; j < 4; ++j) bb[j] = Ks[tx * 4 + j][e];
            #pragma unroll
            for (int i = 0; i < 4; ++i)
                #pragma unroll
                for (int j = 0; j < 4; ++j)
                    s[i][j] = fmaf(a[i], bb[j], s[i][j]);
        }

        const int qr0 = qt * 64 + ty * 4;
        const int kc0 = kt * 64 + tx * 4;
        float rm[4];
        #pragma unroll
        for (int i = 0; i < 4; ++i) {
            #pragma unroll
            for (int j = 0; j < 4; ++j)
                s[i][j] = (kc0 + j <= qr0 + i) ? s[i][j] * scale : -1e30f;
            rm[i] = fmaxf(fmaxf(s[i][0], s[i][1]), fmaxf(s[i][2], s[i][3]));
        }
        // reduce over the 16 tx lanes (lane = (ty&3)*16 + tx inside wave64)
        #pragma unroll
        for (int msk = 1; msk <= 8; msk <<= 1)
            #pragma unroll
            for (int i = 0; i < 4; ++i)
                rm[i] = fmaxf(rm[i], __shfl_xor(rm[i], msk, 64));

        float al[4], p[4][4], rs[4];
        #pragma unroll
        for (int i = 0; i < 4; ++i) {
            const float mn = fmaxf(m_i[i], rm[i]);
            al[i] = __expf(m_i[i] - mn);
            m_i[i] = mn;
            rs[i] = 0.f;
            #pragma unroll
            for (int j = 0; j < 4; ++j) {
                p[i][j] = __expf(s[i][j] - mn);   // masked -> exp(-huge) = 0
                rs[i] += p[i][j];
            }
        }
        #pragma unroll
        for (int msk = 1; msk <= 8; msk <<= 1)
            #pragma unroll
            for (int i = 0; i < 4; ++i)
                rs[i] += __shfl_xor(rs[i], msk, 64);
        #pragma unroll
        for (int i = 0; i < 4; ++i) l_i[i] = l_i[i] * al[i] + rs[i];

        #pragma unroll
        for (int i = 0; i < 4; ++i)
            #pragma unroll
            for (int j = 0; j < 4; ++j)
                Ps[ty * 4 + i][tx * 4 + j] = p[i][j];
        __syncthreads();   // P ready

        #pragma unroll
        for (int i = 0; i < 4; ++i)
            #pragma unroll
            for (int j = 0; j < 4; ++j)
                o_acc[i][j] *= al[i];
        #pragma unroll 8
        for (int kk = 0; kk < 64; ++kk) {
            float a[4];
            #pragma unroll
            for (int i = 0; i < 4; ++i) a[i] = Ps[ty * 4 + i][kk];
            const float4 vv = *(const float4*)&Vs[kk][tx * 4];
            #pragma unroll
            for (int i = 0; i < 4; ++i) {
                o_acc[i][0] = fmaf(a[i], vv.x, o_acc[i][0]);
                o_acc[i][1] = fmaf(a[i], vv.y, o_acc[i][1]);
                o_acc[i][2] = fmaf(a[i], vv.z, o_acc[i][2]);
                o_acc[i][3] = fmaf(a[i], vv.w, o_acc[i][3]);
            }
        }
    }

    // write concat-head layout [B][T][H*HS]
    const int b = bh >> 4, h = bh & 15;
    float* ob = o + ((size_t)b * Tn + qt * 64) * (Hn * HSn) + h * HSn;
    #pragma unroll
    for (int i = 0; i < 4; ++i) {
        const float inv = 1.0f / l_i[i];
        float4 t;
        t.x = o_acc[i][0] * inv; t.y = o_acc[i][1] * inv;
        t.z = o_acc[i][2] * inv; t.w = o_acc[i][3] * inv;
        *(float4*)(ob + (size_t)(ty * 4 + i) * (Hn * HSn) + tx * 4) = t;
    }
}

// ---------------------------------------------------------------------------
// Output projection: [B*T x 1024] @ Wo [1024 x 1024] + bo
// grid: (B*T/64, D/64), block 256.
// ---------------------------------------------------------------------------
__global__ __launch_bounds__(256) void proj_kernel(
    const float* __restrict__ xo, const float* __restrict__ Wo,
    const float* __restrict__ bo, float* __restrict__ out)
{
    const int m0 = blockIdx.x * 64;
    const int n0 = blockIdx.y * 64;
    __shared__ float Xs[64][33];
    __shared__ float Ws[32][64];
    const int tid = threadIdx.x;
    const int ty = tid >> 4, tx = tid & 15;
    float acc[4][4] = {};

    for (int k0 = 0; k0 < Hn * HSn; k0 += 32) {
        {
            const int r  = tid >> 3;
            const int c4 = (tid & 7) << 2;
            #pragma unroll
            for (int p = 0; p < 2; ++p) {
                const float4 t = *(const float4*)(xo + (size_t)(m0 + r + p * 32) * (Hn * HSn) + k0 + c4);
                Xs[r + p * 32][c4 + 0] = t.x; Xs[r + p * 32][c4 + 1] = t.y;
                Xs[r + p * 32][c4 + 2] = t.z; Xs[r + p * 32][c4 + 3] = t.w;
            }
            const int rw = tid >> 4;
            const int cw = (tid & 15) << 2;
            #pragma unroll
            for (int p = 0; p < 2; ++p)
                *(float4*)&Ws[rw + p * 16][cw] =
                    *(const float4*)(Wo + (size_t)(k0 + rw + p * 16) * Dn + n0 + cw);
        }
        __syncthreads();
        #pragma unroll
        for (int kk = 0; kk < 32; ++kk) {
            float a[4];
            #pragma unroll
            for (int i = 0; i < 4; ++i) a[i] = Xs[ty * 4 + i][kk];
            const float4 bv = *(const float4*)&Ws[kk][tx * 4];
            #pragma unroll
            for (int i = 0; i < 4; ++i) {
                acc[i][0] = fmaf(a[i], bv.x, acc[i][0]);
                acc[i][1] = fmaf(a[i], bv.y, acc[i][1]);
                acc[i][2] = fmaf(a[i], bv.z, acc[i][2]);
                acc[i][3] = fmaf(a[i], bv.w, acc[i][3]);
            }
        }
        __syncthreads();
    }
    const float4 bv = *(const float4*)(bo + n0 + tx * 4);
    #pragma unroll
    for (int i = 0; i < 4; ++i) {
        float4 t;
        t.x = acc[i][0] + bv.x; t.y = acc[i][1] + bv.y;
        t.z = acc[i][2] + bv.z; t.w = acc[i][3] + bv.w;
        *(float4*)(out + (size_t)(m0 + ty * 4 + i) * Dn + n0 + tx * 4) = t;
    }
}

extern "C" void kernel_launch(void* const* d_in, const int* in_sizes, int n_in,
                              void* d_out, int out_size, void* d_ws, size_t ws_size,
                              hipStream_t stream) {
    const float* x  = (const float*)d_in[0];
    const float* Wq = (const float*)d_in[1];
    const float* Wk = (const float*)d_in[2];
    const float* Wv = (const float*)d_in[3];
    const float* Wo = (const float*)d_in[4];
    const float* bo = (const float*)d_in[5];
    float* outp = (float*)d_out;

    const size_t per = (size_t)Bn * Hn * Tn * HSn;   // 8M floats = 32 MB
    float* qbuf = (float*)d_ws;
    float* kbuf = qbuf + per;
    float* vbuf = kbuf + per;
    float* obuf = vbuf + per;   // total 128 MB workspace

    qkv_kernel<<<dim3(Tn / 64, 3 * Bn * Hn), 256, 0, stream>>>(x, Wq, Wk, Wv, qbuf, kbuf, vbuf);
    attn_kernel<<<dim3(Tn / 64, Bn * Hn), 256, 0, stream>>>(qbuf, kbuf, vbuf, obuf);
    proj_kernel<<<dim3((Bn * Tn) / 64, Dn / 64), 256, 0, stream>>>(obuf, Wo, bo, outp);
}

// Round 2
// 363.466 us; speedup vs baseline: 6.1978x; 6.1978x over previous
//
#include <hip/hip_runtime.h>

typedef __attribute__((ext_vector_type(8))) short short8v;
typedef __attribute__((ext_vector_type(4))) short short4v;
typedef __attribute__((ext_vector_type(4))) float floatx4;

namespace {
constexpr int Bn = 4, Tn = 2048, Dn = 1024, Hn = 16, HSn = 64;
}

__device__ __forceinline__ short f2bf(float f) {
  unsigned u = __builtin_bit_cast(unsigned, f);
  u += 0x7fffu + ((u >> 16) & 1u);           // round-to-nearest-even
  return (short)(u >> 16);
}

typedef const __attribute__((address_space(1))) unsigned int guint_t;
typedef __attribute__((address_space(3))) unsigned int luint_t;

__device__ __forceinline__ void gload16(const void* g, void* l) {
  __builtin_amdgcn_global_load_lds((guint_t*)g, (luint_t*)l, 16, 0, 0);
}

// swizzled LDS read of 8 contiguous bf16 at (row, k-element) for 128B rows
__device__ __forceinline__ short8v rd8(const char* base, int row, int kel) {
  return *(const short8v*)(base + row * 128 + ((kel * 2) ^ ((row & 7) << 4)));
}

// ---------------------------------------------------------------------------
__global__ __launch_bounds__(256) void cvt_x_k(const float* __restrict__ x, short* __restrict__ xb) {
  const size_t i = ((size_t)blockIdx.x * 256 + threadIdx.x) * 8;
  const float4 a = *(const float4*)(x + i);
  const float4 b = *(const float4*)(x + i + 4);
  short8v o;
  o[0] = f2bf(a.x); o[1] = f2bf(a.y); o[2] = f2bf(a.z); o[3] = f2bf(a.w);
  o[4] = f2bf(b.x); o[5] = f2bf(b.y); o[6] = f2bf(b.z); o[7] = f2bf(b.w);
  *(short8v*)(xb + i) = o;
}

// Wq/Wk/Wv [H][D][HS] fp32 -> wt bf16 [proj*1024 + h*64 + e][d]   (B^T layout)
__global__ __launch_bounds__(256) void tr_wqkv_k(const float* __restrict__ Wq, const float* __restrict__ Wk,
                                                 const float* __restrict__ Wv, short* __restrict__ wt) {
  const int ph = blockIdx.x;            // proj*16 + h
  const int p = ph >> 4, h = ph & 15;
  const int dt = blockIdx.y;            // d-tile 0..15
  const float* W = p == 0 ? Wq : p == 1 ? Wk : Wv;
  __shared__ float T[64][65];
  const int t = threadIdx.x;
  const int rr = t >> 2, c0 = (t & 3) * 4;
  const float* src = W + (size_t)h * (Dn * HSn) + (size_t)(dt * 64 + rr) * HSn;
  #pragma unroll
  for (int q = 0; q < 4; ++q) {
    const float4 v = *(const float4*)(src + c0 + q * 16);
    T[rr][c0 + q * 16 + 0] = v.x; T[rr][c0 + q * 16 + 1] = v.y;
    T[rr][c0 + q * 16 + 2] = v.z; T[rr][c0 + q * 16 + 3] = v.w;
  }
  __syncthreads();
  short* dst = wt + ((size_t)p * 1024 + h * 64 + rr) * 1024 + dt * 64;
  #pragma unroll
  for (int q = 0; q < 4; ++q) {
    const int dl = c0 + q * 16;
    short4v ov = {f2bf(T[dl + 0][rr]), f2bf(T[dl + 1][rr]),
                  f2bf(T[dl + 2][rr]), f2bf(T[dl + 3][rr])};
    *(short4v*)(dst + dl) = ov;
  }
}

// Wo [1024][1024] fp32 -> wot bf16 [n][k]
__global__ __launch_bounds__(256) void tr_wo_k(const float* __restrict__ Wo, short* __restrict__ wot) {
  const int ktile = blockIdx.x, ntile = blockIdx.y;
  __shared__ float T[64][65];
  const int t = threadIdx.x;
  const int rr = t >> 2, c0 = (t & 3) * 4;
  const float* src = Wo + (size_t)(ktile * 64 + rr) * Dn + ntile * 64;
  #pragma unroll
  for (int q = 0; q < 4; ++q) {
    const float4 v = *(const float4*)(src + c0 + q * 16);
    T[rr][c0 + q * 16 + 0] = v.x; T[rr][c0 + q * 16 + 1] = v.y;
    T[rr][c0 + q * 16 + 2] = v.z; T[rr][c0 + q * 16 + 3] = v.w;
  }
  __syncthreads();
  short* dst = wot + (size_t)(ntile * 64 + rr) * 1024 + ktile * 64;
  #pragma unroll
  for (int q = 0; q < 4; ++q) {
    const int dl = c0 + q * 16;
    short4v ov = {f2bf(T[dl + 0][rr]), f2bf(T[dl + 1][rr]),
                  f2bf(T[dl + 2][rr]), f2bf(T[dl + 3][rr])};
    *(short4v*)(dst + dl) = ov;
  }
}

// ---------------------------------------------------------------------------
// 128x128 tile MFMA mainloop, K=1024, BK=64, 256 threads / 4 waves.
// gA -> row m0, k0 of A [m][k]; gB -> row n0 of B^T [n][k]; both row stride 2048B.
__device__ __forceinline__ void gemm_mainloop(const char* gA, const char* gB, char* As, char* Bs,
                                              floatx4 acc[4][4]) {
  const int tid = threadIdx.x;
  const int wv = tid >> 6, ln = tid & 63;
  const int wr = wv >> 1, wc = wv & 1;
  const int lr = ln >> 3, lg = ln & 7;
  const int fr = ln & 15, kq = ln >> 4;
  for (int kt = 0; kt < 16; ++kt) {
    __syncthreads();                          // prev-iter reads done
    #pragma unroll
    for (int c = 0; c < 4; ++c) {
      const int r = wv * 32 + c * 8 + lr;
      const int sw = (lg * 16) ^ ((r & 7) * 16);   // pre-swizzled source, linear LDS dst
      gload16(gA + (size_t)r * 2048 + kt * 128 + sw, As + (wv * 32 + c * 8) * 128);
      gload16(gB + (size_t)r * 2048 + kt * 128 + sw, Bs + (wv * 32 + c * 8) * 128);
    }
    __syncthreads();                          // drains vmcnt -> tiles ready
    #pragma unroll
    for (int kb = 0; kb < 2; ++kb) {
      const int k0 = kb * 32 + kq * 8;
      short8v af[4], bfr[4];
      #pragma unroll
      for (int i = 0; i < 4; ++i) af[i] = rd8(As, wr * 64 + i * 16 + fr, k0);
      #pragma unroll
      for (int j = 0; j < 4; ++j) bfr[j] = rd8(Bs, wc * 64 + j * 16 + fr, k0);
      #pragma unroll
      for (int i = 0; i < 4; ++i)
        #pragma unroll
        for (int j = 0; j < 4; ++j)
          acc[i][j] = __builtin_amdgcn_mfma_f32_16x16x32_bf16(af[i], bfr[j], acc[i][j], 0, 0, 0);
    }
  }
}

// fused QKV: [8192 x 1024] @ [1024 x 3072]; q,k -> [bh][t][e] bf16 (q pre-scaled 1/8),
// v -> [bh][e][t] bf16 (pre-transposed for attention PV B-operand)
__global__ __launch_bounds__(256) void gemm_qkv_k(const short* __restrict__ xb, const short* __restrict__ wt,
                                                  short* __restrict__ qb, short* __restrict__ kb,
                                                  short* __restrict__ vb) {
  __shared__ __align__(16) char As[16384];
  __shared__ __align__(16) char Bs[16384];
  const int m0 = blockIdx.x * 128, n0 = blockIdx.y * 128;
  floatx4 acc[4][4];
  #pragma unroll
  for (int i = 0; i < 4; ++i)
    #pragma unroll
    for (int j = 0; j < 4; ++j) acc[i][j] = floatx4{0.f, 0.f, 0.f, 0.f};
  gemm_mainloop((const char*)xb + (size_t)m0 * 2048, (const char*)wt + (size_t)n0 * 2048, As, Bs, acc);

  const int tid = threadIdx.x, wv = tid >> 6, ln = tid & 63;
  const int wr = wv >> 1, wc = wv & 1;
  const int proj = n0 >> 10;                 // 1024 % 128 == 0 -> uniform per block
  const int b = m0 >> 11;
  const int rb_ = (ln >> 4) * 4, fc = ln & 15;
  if (proj < 2) {
    short* dst = proj == 0 ? qb : kb;
    const float sc = proj == 0 ? 0.125f : 1.0f;
    #pragma unroll
    for (int i = 0; i < 4; ++i) {
      const int m = m0 + wr * 64 + i * 16 + rb_;
      #pragma unroll
      for (int j = 0; j < 4; ++j) {
        const int n = n0 + wc * 64 + j * 16 + fc;
        const int h = (n >> 6) & 15, e = n & 63;
        short* dp = dst + ((size_t)(b * 16 + h) * Tn + (m & 2047)) * 64 + e;
        #pragma unroll
        for (int r = 0; r < 4; ++r) dp[(size_t)r * 64] = f2bf(acc[i][j][r] * sc);
      }
    }
  } else {
    #pragma unroll
    for (int i = 0; i < 4; ++i) {
      const int m = m0 + wr * 64 + i * 16 + rb_;
      const int t0 = m & 2047;
      #pragma unroll
      for (int j = 0; j < 4; ++j) {
        const int n = n0 + wc * 64 + j * 16 + fc;
        const int h = (n >> 6) & 15, e = n & 63;
        short4v ov = {f2bf(acc[i][j][0]), f2bf(acc[i][j][1]),
                      f2bf(acc[i][j][2]), f2bf(acc[i][j][3])};
        *(short4v*)(vb + ((size_t)(b * 16 + h) * 64 + e) * Tn + t0) = ov;
      }
    }
  }
}

// ---------------------------------------------------------------------------
// MFMA flash attention: grid (qt=T/64, bh=B*H), 4 waves x 16 q-rows.
__global__ __launch_bounds__(256) void attn_k(const short* __restrict__ qg, const short* __restrict__ kg,
                                              const short* __restrict__ vg, short* __restrict__ og) {
  __shared__ __align__(16) char Qs[8192];
  __shared__ __align__(16) char Ks[8192];
  __shared__ __align__(16) char Vs[8192];   // holds V^T tile: rows=e, cols=kv
  __shared__ __align__(16) char Ps[8192];
  const int qt = blockIdx.x, bh = blockIdx.y;
  const int tid = threadIdx.x, wv = tid >> 6, ln = tid & 63;
  const int lr = ln >> 3, lg = ln & 7;
  const int fr = ln & 15, kq = ln >> 4;
  const char* qbase = (const char*)qg + (size_t)bh * Tn * 128;
  const char* kbase = (const char*)kg + (size_t)bh * Tn * 128;
  const char* vbase = (const char*)vg + (size_t)bh * Tn * 128;  // [e][t], row stride 4096B

  #pragma unroll
  for (int c = 0; c < 2; ++c) {
    const int r = wv * 16 + c * 8 + lr;
    const int sw = (lg * 16) ^ ((r & 7) * 16);
    gload16(qbase + (size_t)(qt * 64 + r) * 128 + sw, Qs + (wv * 16 + c * 8) * 128);
  }
  floatx4 o[4];
  #pragma unroll
  for (int f = 0; f < 4; ++f) o[f] = floatx4{0.f, 0.f, 0.f, 0.f};
  float m_i[4], l_i[4];
  #pragma unroll
  for (int r = 0; r < 4; ++r) { m_i[r] = -1e30f; l_i[r] = 0.f; }

  for (int kt = 0; kt <= qt; ++kt) {
    __syncthreads();                      // prev PV done (K/V/P safe to touch)
    #pragma unroll
    for (int c = 0; c < 2; ++c) {
      const int r = wv * 16 + c * 8 + lr;
      const int sw = (lg * 16) ^ ((r & 7) * 16);
      gload16(kbase + (size_t)(kt * 64 + r) * 128 + sw, Ks + (wv * 16 + c * 8) * 128);
      gload16(vbase + (size_t)r * 4096 + (size_t)kt * 128 + sw, Vs + (wv * 16 + c * 8) * 128);
    }
    __syncthreads();                      // drains vmcnt -> Q,K,V^T ready

    floatx4 s[4];
    #pragma unroll
    for (int f = 0; f < 4; ++f) s[f] = floatx4{0.f, 0.f, 0.f, 0.f};
    #pragma unroll
    for (int kb = 0; kb < 2; ++kb) {
      const int k0 = kb * 32 + kq * 8;
      const short8v aq = rd8(Qs, wv * 16 + fr, k0);
      #pragma unroll
      for (int f = 0; f < 4; ++f)
        s[f] = __builtin_amdgcn_mfma_f32_16x16x32_bf16(aq, rd8(Ks, f * 16 + fr, k0), s[f], 0, 0, 0);
    }
    if (kt == qt) {                       // causal mask, diag tile only
      #pragma unroll
      for (int f = 0; f < 4; ++f)
        #pragma unroll
        for (int r = 0; r < 4; ++r)
          if (f * 16 + fr > wv * 16 + kq * 4 + r) s[f][r] = -3.0e38f;
    }
    float rm[4], al[4], rs[4], p[4][4];
    #pragma unroll
    for (int r = 0; r < 4; ++r)
      rm[r] = fmaxf(fmaxf(s[0][r], s[1][r]), fmaxf(s[2][r], s[3][r]));
    #pragma unroll
    for (int st = 0; st < 4; ++st)
      #pragma unroll
      for (int r = 0; r < 4; ++r) rm[r] = fmaxf(rm[r], __shfl_xor(rm[r], 1 << st, 64));
    #pragma unroll
    for (int r = 0; r < 4; ++r) {
      const float mn = fmaxf(m_i[r], rm[r]);
      al[r] = __expf(m_i[r] - mn);
      m_i[r] = mn;
      rs[r] = 0.f;
    }
    #pragma unroll
    for (int f = 0; f < 4; ++f)
      #pragma unroll
      for (int r = 0; r < 4; ++r) {
        p[f][r] = __expf(s[f][r] - m_i[r]);
        rs[r] += p[f][r];
      }
    #pragma unroll
    for (int st = 0; st < 4; ++st)
      #pragma unroll
      for (int r = 0; r < 4; ++r) rs[r] += __shfl_xor(rs[r], 1 << st, 64);
    #pragma unroll
    for (int r = 0; r < 4; ++r) l_i[r] = l_i[r] * al[r] + rs[r];

    // P (C-layout) -> swizzled LDS so PV can read it as an A-fragment
    #pragma unroll
    for (int f = 0; f < 4; ++f)
      #pragma unroll
      for (int r = 0; r < 4; ++r) {
        const int row = wv * 16 + kq * 4 + r;
        const int cb = (f * 16 + fr) * 2;
        *(short*)(Ps + row * 128 + (cb ^ ((row & 7) << 4))) = f2bf(p[f][r]);
      }
    __syncthreads();                      // Ps visible

    #pragma unroll
    for (int f = 0; f < 4; ++f)
      #pragma unroll
      for (int r = 0; r < 4; ++r) o[f][r] *= al[r];
    #pragma unroll
    for (int kb = 0; kb < 2; ++kb) {
      const int k0 = kb * 32 + kq * 8;
      const short8v pa = rd8(Ps, wv * 16 + fr, k0);
      #pragma unroll
      for (int f = 0; f < 4; ++f)
        o[f] = __builtin_amdgcn_mfma_f32_16x16x32_bf16(pa, rd8(Vs, f * 16 + fr, k0), o[f], 0, 0, 0);
    }
  }

  const int b = bh >> 4, h = bh & 15;
  #pragma unroll
  for (int f = 0; f < 4; ++f)
    #pragma unroll
    for (int r = 0; r < 4; ++r) {
      const int trow = qt * 64 + wv * 16 + kq * 4 + r;
      og[((size_t)(b * Tn + trow)) * (Hn * HSn) + h * 64 + f * 16 + fr] = f2bf(o[f][r] / l_i[r]);
    }
}

// ---------------------------------------------------------------------------
// out = ao[8192x1024] @ Wo + bo  (fp32 out)
__global__ __launch_bounds__(256) void gemm_out_k(const short* __restrict__ ao, const short* __restrict__ wot,
                                                  const float* __restrict__ bo, float* __restrict__ out) {
  __shared__ __align__(16) char As[16384];
  __shared__ __align__(16) char Bs[16384];
  const int m0 = blockIdx.x * 128, n0 = blockIdx.y * 128;
  floatx4 acc[4][4];
  #pragma unroll
  for (int i = 0; i < 4; ++i)
    #pragma unroll
    for (int j = 0; j < 4; ++j) acc[i][j] = floatx4{0.f, 0.f, 0.f, 0.f};
  gemm_mainloop((const char*)ao + (size_t)m0 * 2048, (const char*)wot + (size_t)n0 * 2048, As, Bs, acc);

  const int tid = threadIdx.x, wv = tid >> 6, ln = tid & 63;
  const int wr = wv >> 1, wc = wv & 1;
  const int rb_ = (ln >> 4) * 4, fc = ln & 15;
  #pragma unroll
  for (int i = 0; i < 4; ++i) {
    const int m = m0 + wr * 64 + i * 16 + rb_;
    #pragma unroll
    for (int j = 0; j < 4; ++j) {
      const int n = n0 + wc * 64 + j * 16 + fc;
      const float bias = bo[n];
      #pragma unroll
      for (int r = 0; r < 4; ++r) out[(size_t)(m + r) * Dn + n] = acc[i][j][r] + bias;
    }
  }
}

extern "C" void kernel_launch(void* const* d_in, const int* in_sizes, int n_in,
                              void* d_out, int out_size, void* d_ws, size_t ws_size,
                              hipStream_t stream) {
  const float* x  = (const float*)d_in[0];
  const float* Wq = (const float*)d_in[1];
  const float* Wk = (const float*)d_in[2];
  const float* Wv = (const float*)d_in[3];
  const float* Wo = (const float*)d_in[4];
  const float* bo = (const float*)d_in[5];
  float* out = (float*)d_out;

  char* ws = (char*)d_ws;
  short* xb  = (short*)(ws);                      // 16 MB  x bf16 [8192][1024]
  short* wt  = (short*)(ws + (16u << 20));        //  6 MB  Wqkv^T bf16 [3072][1024]
  short* wot = (short*)(ws + (22u << 20));        //  2 MB  Wo^T bf16 [1024][1024]
  short* qb  = (short*)(ws + (24u << 20));        // 16 MB  q bf16 [bh][t][e] (pre-scaled)
  short* kb  = (short*)(ws + (40u << 20));        // 16 MB  k bf16 [bh][t][e]
  short* vb  = (short*)(ws + (56u << 20));        // 16 MB  v^T bf16 [bh][e][t]
  short* ao  = (short*)(ws + (72u << 20));        // 16 MB  attn out bf16 [b][t][1024]

  cvt_x_k<<<4096, 256, 0, stream>>>(x, xb);
  tr_wqkv_k<<<dim3(48, 16), 256, 0, stream>>>(Wq, Wk, Wv, wt);
  tr_wo_k<<<dim3(16, 16), 256, 0, stream>>>(Wo, wot);
  gemm_qkv_k<<<dim3(64, 24), 256, 0, stream>>>(xb, wt, qb, kb, vb);
  attn_k<<<dim3(32, 64), 256, 0, stream>>>(qb, kb, vb, ao);
  gemm_out_k<<<dim3(64, 8), 256, 0, stream>>>(ao, wot, bo, out);
}

// Round 3
// 186.289 us; speedup vs baseline: 12.0925x; 1.9511x over previous
//
#include <hip/hip_runtime.h>

typedef __attribute__((ext_vector_type(8))) short short8v;
typedef __attribute__((ext_vector_type(4))) short short4v;
typedef __attribute__((ext_vector_type(4))) float floatx4;

namespace {
constexpr int Bn = 4, Tn = 2048, Dn = 1024, Hn = 16, HSn = 64;
}

__device__ __forceinline__ short f2bf(float f) {
  unsigned u = __builtin_bit_cast(unsigned, f);
  u += 0x7fffu + ((u >> 16) & 1u);           // round-to-nearest-even
  return (short)(u >> 16);
}

typedef const __attribute__((address_space(1))) unsigned int guint_t;
typedef __attribute__((address_space(3))) unsigned int luint_t;

__device__ __forceinline__ void gload16(const void* g, void* l) {
  __builtin_amdgcn_global_load_lds((guint_t*)g, (luint_t*)l, 16, 0, 0);
}

// swizzled LDS read of 8 contiguous bf16 at (row, k-element) for 128B rows
__device__ __forceinline__ short8v rd8(const char* base, int row, int kel) {
  return *(const short8v*)(base + row * 128 + ((kel * 2) ^ ((row & 7) << 4)));
}

// ---------------------------------------------------------------------------
__global__ __launch_bounds__(256) void cvt_x_k(const float* __restrict__ x, short* __restrict__ xb) {
  const size_t i = ((size_t)blockIdx.x * 256 + threadIdx.x) * 8;
  const float4 a = *(const float4*)(x + i);
  const float4 b = *(const float4*)(x + i + 4);
  short8v o;
  o[0] = f2bf(a.x); o[1] = f2bf(a.y); o[2] = f2bf(a.z); o[3] = f2bf(a.w);
  o[4] = f2bf(b.x); o[5] = f2bf(b.y); o[6] = f2bf(b.z); o[7] = f2bf(b.w);
  *(short8v*)(xb + i) = o;
}

// Wq/Wk/Wv [H][D][HS] fp32 -> wt bf16 [proj*1024 + h*64 + e][d]   (B^T layout)
__global__ __launch_bounds__(256) void tr_wqkv_k(const float* __restrict__ Wq, const float* __restrict__ Wk,
                                                 const float* __restrict__ Wv, short* __restrict__ wt) {
  const int ph = blockIdx.x;            // proj*16 + h
  const int p = ph >> 4, h = ph & 15;
  const int dt = blockIdx.y;            // d-tile 0..15
  const float* W = p == 0 ? Wq : p == 1 ? Wk : Wv;
  __shared__ float T[64][65];
  const int t = threadIdx.x;
  const int rr = t >> 2, c0 = (t & 3) * 4;
  const float* src = W + (size_t)h * (Dn * HSn) + (size_t)(dt * 64 + rr) * HSn;
  #pragma unroll
  for (int q = 0; q < 4; ++q) {
    const float4 v = *(const float4*)(src + c0 + q * 16);
    T[rr][c0 + q * 16 + 0] = v.x; T[rr][c0 + q * 16 + 1] = v.y;
    T[rr][c0 + q * 16 + 2] = v.z; T[rr][c0 + q * 16 + 3] = v.w;
  }
  __syncthreads();
  short* dst = wt + ((size_t)p * 1024 + h * 64 + rr) * 1024 + dt * 64;
  #pragma unroll
  for (int q = 0; q < 4; ++q) {
    const int dl = c0 + q * 16;
    short4v ov = {f2bf(T[dl + 0][rr]), f2bf(T[dl + 1][rr]),
                  f2bf(T[dl + 2][rr]), f2bf(T[dl + 3][rr])};
    *(short4v*)(dst + dl) = ov;
  }
}

// Wo [1024][1024] fp32 -> wot bf16 [n][k]
__global__ __launch_bounds__(256) void tr_wo_k(const float* __restrict__ Wo, short* __restrict__ wot) {
  const int ktile = blockIdx.x, ntile = blockIdx.y;
  __shared__ float T[64][65];
  const int t = threadIdx.x;
  const int rr = t >> 2, c0 = (t & 3) * 4;
  const float* src = Wo + (size_t)(ktile * 64 + rr) * Dn + ntile * 64;
  #pragma unroll
  for (int q = 0; q < 4; ++q) {
    const float4 v = *(const float4*)(src + c0 + q * 16);
    T[rr][c0 + q * 16 + 0] = v.x; T[rr][c0 + q * 16 + 1] = v.y;
    T[rr][c0 + q * 16 + 2] = v.z; T[rr][c0 + q * 16 + 3] = v.w;
  }
  __syncthreads();
  short* dst = wot + (size_t)(ntile * 64 + rr) * 1024 + ktile * 64;
  #pragma unroll
  for (int q = 0; q < 4; ++q) {
    const int dl = c0 + q * 16;
    short4v ov = {f2bf(T[dl + 0][rr]), f2bf(T[dl + 1][rr]),
                  f2bf(T[dl + 2][rr]), f2bf(T[dl + 3][rr])};
    *(short4v*)(dst + dl) = ov;
  }
}

// ---------------------------------------------------------------------------
// 128x128 tile MFMA mainloop, K=1024, BK=64, 256 threads / 4 waves.
__device__ __forceinline__ void gemm_mainloop(const char* gA, const char* gB, char* As, char* Bs,
                                              floatx4 acc[4][4]) {
  const int tid = threadIdx.x;
  const int wv = tid >> 6, ln = tid & 63;
  const int wr = wv >> 1, wc = wv & 1;
  const int lr = ln >> 3, lg = ln & 7;
  const int fr = ln & 15, kq = ln >> 4;
  for (int kt = 0; kt < 16; ++kt) {
    __syncthreads();
    #pragma unroll
    for (int c = 0; c < 4; ++c) {
      const int r = wv * 32 + c * 8 + lr;
      const int sw = (lg * 16) ^ ((r & 7) * 16);
      gload16(gA + (size_t)r * 2048 + kt * 128 + sw, As + (wv * 32 + c * 8) * 128);
      gload16(gB + (size_t)r * 2048 + kt * 128 + sw, Bs + (wv * 32 + c * 8) * 128);
    }
    __syncthreads();
    #pragma unroll
    for (int kb = 0; kb < 2; ++kb) {
      const int k0 = kb * 32 + kq * 8;
      short8v af[4], bfr[4];
      #pragma unroll
      for (int i = 0; i < 4; ++i) af[i] = rd8(As, wr * 64 + i * 16 + fr, k0);
      #pragma unroll
      for (int j = 0; j < 4; ++j) bfr[j] = rd8(Bs, wc * 64 + j * 16 + fr, k0);
      #pragma unroll
      for (int i = 0; i < 4; ++i)
        #pragma unroll
        for (int j = 0; j < 4; ++j)
          acc[i][j] = __builtin_amdgcn_mfma_f32_16x16x32_bf16(af[i], bfr[j], acc[i][j], 0, 0, 0);
    }
  }
}

// fused QKV: q pre-scaled by (1/8)*log2(e) so attention softmax runs in exp2 domain
__global__ __launch_bounds__(256) void gemm_qkv_k(const short* __restrict__ xb, const short* __restrict__ wt,
                                                  short* __restrict__ qb, short* __restrict__ kb,
                                                  short* __restrict__ vb) {
  __shared__ __align__(16) char As[16384];
  __shared__ __align__(16) char Bs[16384];
  const int m0 = blockIdx.x * 128, n0 = blockIdx.y * 128;
  floatx4 acc[4][4];
  #pragma unroll
  for (int i = 0; i < 4; ++i)
    #pragma unroll
    for (int j = 0; j < 4; ++j) acc[i][j] = floatx4{0.f, 0.f, 0.f, 0.f};
  gemm_mainloop((const char*)xb + (size_t)m0 * 2048, (const char*)wt + (size_t)n0 * 2048, As, Bs, acc);

  const int tid = threadIdx.x, wv = tid >> 6, ln = tid & 63;
  const int wr = wv >> 1, wc = wv & 1;
  const int proj = n0 >> 10;
  const int b = m0 >> 11;
  const int rb_ = (ln >> 4) * 4, fc = ln & 15;
  if (proj < 2) {
    short* dst = proj == 0 ? qb : kb;
    const float sc = proj == 0 ? 0.18033688011112042f : 1.0f;  // 0.125*log2e
    #pragma unroll
    for (int i = 0; i < 4; ++i) {
      const int m = m0 + wr * 64 + i * 16 + rb_;
      #pragma unroll
      for (int j = 0; j < 4; ++j) {
        const int n = n0 + wc * 64 + j * 16 + fc;
        const int h = (n >> 6) & 15, e = n & 63;
        short* dp = dst + ((size_t)(b * 16 + h) * Tn + (m & 2047)) * 64 + e;
        #pragma unroll
        for (int r = 0; r < 4; ++r) dp[(size_t)r * 64] = f2bf(acc[i][j][r] * sc);
      }
    }
  } else {
    #pragma unroll
    for (int i = 0; i < 4; ++i) {
      const int m = m0 + wr * 64 + i * 16 + rb_;
      const int t0 = m & 2047;
      #pragma unroll
      for (int j = 0; j < 4; ++j) {
        const int n = n0 + wc * 64 + j * 16 + fc;
        const int h = (n >> 6) & 15, e = n & 63;
        short4v ov = {f2bf(acc[i][j][0]), f2bf(acc[i][j][1]),
                      f2bf(acc[i][j][2]), f2bf(acc[i][j][3])};
        *(short4v*)(vb + ((size_t)(b * 16 + h) * 64 + e) * Tn + t0) = ov;
      }
    }
  }
}

// ---------------------------------------------------------------------------
// Transposed MFMA flash attention: grid (bh, T/128), 4 waves x 32 q-rows.
// S^T = mfma(K, Q): lane owns q-col = ln&15  -> lane-local softmax state.
// O^T = mfma(V^T, P^T): same lane owns O's q-col -> lane-local rescale.
// 2-phase pipeline: prefetch next K/V tile (dbuf) before current compute; 1 barrier/iter.
__global__ __launch_bounds__(256, 3) void attn_k(const short* __restrict__ qg, const short* __restrict__ kg,
                                                 const short* __restrict__ vg, short* __restrict__ og) {
  __shared__ __align__(16) char Qs[16384];     // 128 q-rows; re-used as Ps after Q-frag hoist
  __shared__ __align__(16) char Ks[16384];     // 2 x 64 kv-rows (double buffer)
  __shared__ __align__(16) char Vs[16384];     // 2 x 64 e-rows of V^T (double buffer)
  char* Ps = Qs;
  const int qt = gridDim.y - 1 - blockIdx.y;   // longest causal blocks dispatch first
  const int bh = blockIdx.x;
  const int tid = threadIdx.x, wv = tid >> 6, ln = tid & 63;
  const int lr = ln >> 3, lg = ln & 7;         // staging: row-in-8, 16B chunk
  const int fr = ln & 15, kq = ln >> 4;        // fragment: row/col, k-octet
  const char* qbase = (const char*)qg + (size_t)bh * Tn * 128;
  const char* kbase = (const char*)kg + (size_t)bh * Tn * 128;
  const char* vbase = (const char*)vg + (size_t)bh * Tn * 128;   // [e][t], 4096B rows

  // stage Q tile (128 rows) + first K/V tile
  #pragma unroll
  for (int c = 0; c < 4; ++c) {
    const int r = c * 32 + wv * 8 + lr;
    const int sw = (lg * 16) ^ ((r & 7) * 16);
    gload16(qbase + (size_t)(qt * 128 + r) * 128 + sw, Qs + (c * 32 + wv * 8) * 128);
  }
  #pragma unroll
  for (int c = 0; c < 2; ++c) {
    const int r = c * 32 + wv * 8 + lr;
    const int sw = (lg * 16) ^ ((r & 7) * 16);
    gload16(kbase + (size_t)r * 128 + sw, Ks + (c * 32 + wv * 8) * 128);
    gload16(vbase + (size_t)r * 4096 + sw, Vs + (c * 32 + wv * 8) * 128);
  }
  __syncthreads();

  // hoist Q B-fragments (col = q, depth = e); Qs free after this (aliased by Ps)
  short8v qf[2][2];
  #pragma unroll
  for (int c = 0; c < 2; ++c)
    #pragma unroll
    for (int kb = 0; kb < 2; ++kb)
      qf[c][kb] = rd8(Qs, wv * 32 + c * 16 + fr, kb * 32 + kq * 8);

  floatx4 ot[4][2];                            // O^T acc: [e-group][q-group]
  #pragma unroll
  for (int f = 0; f < 4; ++f) { ot[f][0] = floatx4{0.f,0.f,0.f,0.f}; ot[f][1] = floatx4{0.f,0.f,0.f,0.f}; }
  float m_i[2] = {-1e30f, -1e30f}, l_i[2] = {0.f, 0.f};

  const int nkt = 2 * qt + 2;
  const int q0w = qt * 128 + wv * 32;          // wave's first q-row
  for (int kt = 0; kt < nkt; ++kt) {
    const int cur = kt & 1;
    if (kt + 1 < nkt) {                        // prefetch next tile into other buffer
      #pragma unroll
      for (int c = 0; c < 2; ++c) {
        const int r = c * 32 + wv * 8 + lr;
        const int sw = (lg * 16) ^ ((r & 7) * 16);
        gload16(kbase + (size_t)((kt + 1) * 64 + r) * 128 + sw,
                Ks + (cur ^ 1) * 8192 + (c * 32 + wv * 8) * 128);
        gload16(vbase + (size_t)r * 4096 + (size_t)(kt + 1) * 128 + sw,
                Vs + (cur ^ 1) * 8192 + (c * 32 + wv * 8) * 128);
      }
    }
    if (kt * 64 <= q0w + 31) {                 // skip fully-masked waves
      const char* Ksc = Ks + cur * 8192;
      const char* Vsc = Vs + cur * 8192;
      // S^T = K . Q  (C: row = kv, col = q)
      floatx4 st[2][4];
      #pragma unroll
      for (int f = 0; f < 4; ++f) { st[0][f] = floatx4{0.f,0.f,0.f,0.f}; st[1][f] = floatx4{0.f,0.f,0.f,0.f}; }
      #pragma unroll
      for (int kb = 0; kb < 2; ++kb) {
        const int e0 = kb * 32 + kq * 8;
        #pragma unroll
        for (int f = 0; f < 4; ++f) {
          const short8v kf = rd8(Ksc, f * 16 + fr, e0);
          st[0][f] = __builtin_amdgcn_mfma_f32_16x16x32_bf16(kf, qf[0][kb], st[0][f], 0, 0, 0);
          st[1][f] = __builtin_amdgcn_mfma_f32_16x16x32_bf16(kf, qf[1][kb], st[1][f], 0, 0, 0);
        }
      }
      if (kt * 64 + 63 > q0w) {                // causal mask (diag-overlapping tiles)
        #pragma unroll
        for (int c = 0; c < 2; ++c) {
          const int q = q0w + c * 16 + fr;
          #pragma unroll
          for (int f = 0; f < 4; ++f)
            #pragma unroll
            for (int r = 0; r < 4; ++r)
              if (kt * 64 + f * 16 + kq * 4 + r > q) st[c][f][r] = -3.0e38f;
        }
      }
      float al[2];
      #pragma unroll
      for (int c = 0; c < 2; ++c) {
        float mx = st[c][0][0];
        #pragma unroll
        for (int f = 0; f < 4; ++f)
          #pragma unroll
          for (int r = 0; r < 4; ++r) mx = fmaxf(mx, st[c][f][r]);
        mx = fmaxf(mx, __shfl_xor(mx, 16, 64));
        mx = fmaxf(mx, __shfl_xor(mx, 32, 64));
        const float mn = fmaxf(m_i[c], mx);
        al[c] = exp2f(m_i[c] - mn);
        m_i[c] = mn;
        float sum = 0.f;
        const int prow = wv * 32 + c * 16 + fr;
        #pragma unroll
        for (int f = 0; f < 4; ++f) {
          const float p0 = exp2f(st[c][f][0] - mn);
          const float p1 = exp2f(st[c][f][1] - mn);
          const float p2 = exp2f(st[c][f][2] - mn);
          const float p3 = exp2f(st[c][f][3] - mn);
          sum += (p0 + p1) + (p2 + p3);
          short4v pv = {f2bf(p0), f2bf(p1), f2bf(p2), f2bf(p3)};
          *(short4v*)(Ps + prow * 128 + ((f * 32 + kq * 8) ^ ((prow & 7) * 16))) = pv;
        }
        sum += __shfl_xor(sum, 16, 64);
        sum += __shfl_xor(sum, 32, 64);
        l_i[c] = l_i[c] * al[c] + sum;
      }
      #pragma unroll
      for (int f = 0; f < 4; ++f) { ot[f][0] *= al[0]; ot[f][1] *= al[1]; }
      // O^T += V^T . P^T  (A: V^T rows=e, B: P^T cols=q; both wave-local reads)
      #pragma unroll
      for (int kb = 0; kb < 2; ++kb) {
        const int v0 = kb * 32 + kq * 8;
        const short8v pb0 = rd8(Ps, wv * 32 + fr, v0);
        const short8v pb1 = rd8(Ps, wv * 32 + 16 + fr, v0);
        #pragma unroll
        for (int f = 0; f < 4; ++f) {
          const short8v vf = rd8(Vsc, f * 16 + fr, v0);
          ot[f][0] = __builtin_amdgcn_mfma_f32_16x16x32_bf16(vf, pb0, ot[f][0], 0, 0, 0);
          ot[f][1] = __builtin_amdgcn_mfma_f32_16x16x32_bf16(vf, pb1, ot[f][1], 0, 0, 0);
        }
      }
    }
    __syncthreads();                           // drains prefetch; frees cur for overwrite
  }

  const int b = bh >> 4, h = bh & 15;
  #pragma unroll
  for (int c = 0; c < 2; ++c) {
    const float inv = 1.0f / l_i[c];
    const size_t t = (size_t)(b * Tn + qt * 128 + wv * 32 + c * 16 + fr);
    #pragma unroll
    for (int f = 0; f < 4; ++f) {
      short4v o4 = {f2bf(ot[f][c][0] * inv), f2bf(ot[f][c][1] * inv),
                    f2bf(ot[f][c][2] * inv), f2bf(ot[f][c][3] * inv)};
      *(short4v*)(og + t * 1024 + h * 64 + f * 16 + kq * 4) = o4;
    }
  }
}

// ---------------------------------------------------------------------------
__global__ __launch_bounds__(256) void gemm_out_k(const short* __restrict__ ao, const short* __restrict__ wot,
                                                  const float* __restrict__ bo, float* __restrict__ out) {
  __shared__ __align__(16) char As[16384];
  __shared__ __align__(16) char Bs[16384];
  const int m0 = blockIdx.x * 128, n0 = blockIdx.y * 128;
  floatx4 acc[4][4];
  #pragma unroll
  for (int i = 0; i < 4; ++i)
    #pragma unroll
    for (int j = 0; j < 4; ++j) acc[i][j] = floatx4{0.f, 0.f, 0.f, 0.f};
  gemm_mainloop((const char*)ao + (size_t)m0 * 2048, (const char*)wot + (size_t)n0 * 2048, As, Bs, acc);

  const int tid = threadIdx.x, wv = tid >> 6, ln = tid & 63;
  const int wr = wv >> 1, wc = wv & 1;
  const int rb_ = (ln >> 4) * 4, fc = ln & 15;
  #pragma unroll
  for (int i = 0; i < 4; ++i) {
    const int m = m0 + wr * 64 + i * 16 + rb_;
    #pragma unroll
    for (int j = 0; j < 4; ++j) {
      const int n = n0 + wc * 64 + j * 16 + fc;
      const float bias = bo[n];
      #pragma unroll
      for (int r = 0; r < 4; ++r) out[(size_t)(m + r) * Dn + n] = acc[i][j][r] + bias;
    }
  }
}

extern "C" void kernel_launch(void* const* d_in, const int* in_sizes, int n_in,
                              void* d_out, int out_size, void* d_ws, size_t ws_size,
                              hipStream_t stream) {
  const float* x  = (const float*)d_in[0];
  const float* Wq = (const float*)d_in[1];
  const float* Wk = (const float*)d_in[2];
  const float* Wv = (const float*)d_in[3];
  const float* Wo = (const float*)d_in[4];
  const float* bo = (const float*)d_in[5];
  float* out = (float*)d_out;

  char* ws = (char*)d_ws;
  short* xb  = (short*)(ws);                      // 16 MB  x bf16 [8192][1024]
  short* wt  = (short*)(ws + (16u << 20));        //  6 MB  Wqkv^T bf16 [3072][1024]
  short* wot = (short*)(ws + (22u << 20));        //  2 MB  Wo^T bf16 [1024][1024]
  short* qb  = (short*)(ws + (24u << 20));        // 16 MB  q bf16 [bh][t][e] (pre-scaled, log2e folded)
  short* kb  = (short*)(ws + (40u << 20));        // 16 MB  k bf16 [bh][t][e]
  short* vb  = (short*)(ws + (56u << 20));        // 16 MB  v^T bf16 [bh][e][t]
  short* ao  = (short*)(ws + (72u << 20));        // 16 MB  attn out bf16 [b][t][1024]

  cvt_x_k<<<4096, 256, 0, stream>>>(x, xb);
  tr_wqkv_k<<<dim3(48, 16), 256, 0, stream>>>(Wq, Wk, Wv, wt);
  tr_wo_k<<<dim3(16, 16), 256, 0, stream>>>(Wo, wot);
  gemm_qkv_k<<<dim3(64, 24), 256, 0, stream>>>(xb, wt, qb, kb, vb);
  attn_k<<<dim3(64, 16), 256, 0, stream>>>(qb, kb, vb, ao);
  gemm_out_k<<<dim3(64, 8), 256, 0, stream>>>(ao, wot, bo, out);
}